// Round 20
// baseline (83.995 us; speedup 1.0000x reference)
//
#include <hip/hip_runtime.h>
#include <hip/hip_bf16.h>

// SelfAttentionBlock: B=4, C=256, RC=128, H=W=64 (N=4096)
// Round 20 (on round-19 verified base, 73.4us) — k_attn loop VALU diet:
//  (1) l-accumulation via ones-MFMA: acc_l = mfma_fp8(P, ONES, acc_l) replaces
//      14 VALU adds/iter + the end-of-loop shuffle reduce. l now sums the
//      QUANTIZED P, exactly matching the PV numerator.
//  (2) s zero-init via zero-C operand on the ks=0 MFMA (16 movs/iter -> 4
//      loop-invariant movs).
// k_qkv / k_out byte-identical to round 19.

#define B_   4
#define C_   256
#define RC_  128
#define N_   4096
#define SCALEL 0.12750880597462906f                // (1/sqrt(128)) * log2(e)

typedef __bf16 bf16x8 __attribute__((ext_vector_type(8)));
typedef unsigned short u16x8 __attribute__((ext_vector_type(8)));
typedef float f32x4 __attribute__((ext_vector_type(4)));

static __device__ __forceinline__ unsigned short f2bf(float f) {
    unsigned int u = __builtin_bit_cast(unsigned int, f);
    u += 0x7fffu + ((u >> 16) & 1u);
    return (unsigned short)(u >> 16);
}

static __device__ __forceinline__ f32x4 mfma16(u16x8 a, u16x8 b, f32x4 c) {
    return __builtin_amdgcn_mfma_f32_16x16x32_bf16(
        __builtin_bit_cast(bf16x8, a), __builtin_bit_cast(bf16x8, b), c, 0, 0, 0);
}

static __device__ __forceinline__ unsigned int cvtpk(float lo, float hi) {
    unsigned int r;
    asm("v_cvt_pk_bf16_f32 %0, %1, %2" : "=v"(r) : "v"(lo), "v"(hi));
    return r;   // low 16 = bf16(lo), high 16 = bf16(hi), RNE
}

// load 8 consecutive f32 weights and pack to bf16x8 (same RNE as f2bf)
static __device__ __forceinline__ u16x8 ldw8(const float* p) {
    float4 f0 = *(const float4*)p;
    float4 f1 = *(const float4*)(p + 4);
    int4 pk;
    pk.x = (int)cvtpk(f0.x, f0.y);
    pk.y = (int)cvtpk(f0.z, f0.w);
    pk.z = (int)cvtpk(f1.x, f1.y);
    pk.w = (int)cvtpk(f1.z, f1.w);
    return __builtin_bit_cast(u16x8, pk);
}

// pack 4 f32 -> 4 fp8 e4m3 bytes
static __device__ __forceinline__ int pk4fp8(float a, float b, float c, float d) {
    int w = __builtin_amdgcn_cvt_pk_fp8_f32(a, b, 0, false);
    w = __builtin_amdgcn_cvt_pk_fp8_f32(c, d, w, true);
    return w;
}

static __device__ __forceinline__ void gl_lds16(const void* g, void* l) {
    __builtin_amdgcn_global_load_lds(
        (const __attribute__((address_space(1))) void*)g,
        (__attribute__((address_space(3))) void*)l, 16, 0, 0);
}

// ---------------- kernel 1: QKV projection (QBLK=64; round-18 verified) ----------------
#define K1_LDA 264  // 256 + 8 pad (shorts)

__global__ __launch_bounds__(256) void k_qkv(
    const float* __restrict__ x,
    const float* __restrict__ wq, const float* __restrict__ wk, const float* __restrict__ wv,
    const float* __restrict__ bq, const float* __restrict__ bk, const float* __restrict__ bv,
    unsigned char* __restrict__ Qf, unsigned char* __restrict__ Kf,
    unsigned char* __restrict__ Vt8)
{
    __shared__ unsigned short lds[64 * K1_LDA];   // 67.6 KB
    const int b  = blockIdx.y;
    const int n0 = blockIdx.x * 64;
    const int t  = threadIdx.x;
    const int lane = t & 63, wv_ = t >> 6;
    const int g = lane >> 4, q16 = lane & 15;

    // stage x[b][c][n0+tok] -> lds[tok][c]; 4 consecutive tokens x 16 channels
    {
        int tk0 = (t & 15) * 4;
        int cb  = (t >> 4) * 16;
        const float* xb = x + ((size_t)b * C_ * N_) + n0 + tk0;
        float4 col[16];
        #pragma unroll
        for (int e = 0; e < 16; ++e)
            col[e] = *(const float4*)&xb[(size_t)(cb + e) * N_];
        #pragma unroll
        for (int tk = 0; tk < 4; ++tk) {
            #pragma unroll
            for (int h = 0; h < 2; ++h) {
                u16x8 v;
                #pragma unroll
                for (int e = 0; e < 8; ++e) {
                    float f = (tk == 0) ? col[h * 8 + e].x : (tk == 1) ? col[h * 8 + e].y
                            : (tk == 2) ? col[h * 8 + e].z : col[h * 8 + e].w;
                    v[e] = f2bf(f);
                }
                *(u16x8*)&lds[(tk0 + tk) * K1_LDA + cb + h * 8] = v;
            }
        }
    }
    __syncthreads();

    f32x4 acc[3][2][4];   // [tq][r2][nf]
    #pragma unroll
    for (int tq = 0; tq < 3; ++tq)
        #pragma unroll
        for (int r2 = 0; r2 < 2; ++r2)
            #pragma unroll
            for (int nf = 0; nf < 4; ++nf)
                acc[tq][r2][nf] = (f32x4){0.f, 0.f, 0.f, 0.f};

    const float* wsrc[3] = {wq, wk, wv};
    const int rbase = wv_ * 32;
    #pragma unroll
    for (int ks = 0; ks < 8; ++ks) {
        u16x8 a[4];
        #pragma unroll
        for (int nf = 0; nf < 4; ++nf)
            a[nf] = *(const u16x8*)&lds[(nf * 16 + q16) * K1_LDA + ks * 32 + g * 8];
        #pragma unroll
        for (int tq = 0; tq < 3; ++tq) {
            const float* w = wsrc[tq];
            #pragma unroll
            for (int r2 = 0; r2 < 2; ++r2) {
                u16x8 bf = ldw8(&w[(size_t)(rbase + r2 * 16 + q16) * 256 + ks * 32 + g * 8]);
                #pragma unroll
                for (int nf = 0; nf < 4; ++nf) {
                    if (tq < 2)
                        acc[tq][r2][nf] = mfma16(bf, a[nf], acc[tq][r2][nf]);  // swapped
                    else
                        acc[tq][r2][nf] = mfma16(a[nf], bf, acc[tq][r2][nf]);
                }
            }
        }
    }

    // Q (pre-scaled by SCALEL), K: fp8 e4m3 dword stores (4 consecutive r/thread)
    #pragma unroll
    for (int r2 = 0; r2 < 2; ++r2) {
        int rb = rbase + r2 * 16 + g * 4;
        float4 bq4 = *(const float4*)&bq[rb];
        float4 bk4 = *(const float4*)&bk[rb];
        #pragma unroll
        for (int nf = 0; nf < 4; ++nf) {
            int n = n0 + nf * 16 + q16;
            int qw32 = pk4fp8((acc[0][r2][nf][0] + bq4.x) * SCALEL,
                              (acc[0][r2][nf][1] + bq4.y) * SCALEL,
                              (acc[0][r2][nf][2] + bq4.z) * SCALEL,
                              (acc[0][r2][nf][3] + bq4.w) * SCALEL);
            int kw32 = pk4fp8(acc[1][r2][nf][0] + bk4.x, acc[1][r2][nf][1] + bk4.y,
                              acc[1][r2][nf][2] + bk4.z, acc[1][r2][nf][3] + bk4.w);
            size_t base = ((size_t)b * N_ + n) * RC_ + rb;
            *(unsigned int*)(Qf + base) = (unsigned int)qw32;
            *(unsigned int*)(Kf + base) = (unsigned int)kw32;
        }
    }

    // V: fp8 e4m3 image, stride 40 B per channel row (round-8-verified mapping).
    #pragma unroll
    for (int r2 = 0; r2 < 2; ++r2) {
        int r = rbase + r2 * 16 + q16;
        float biasv = bv[r];
        #pragma unroll
        for (int nf = 0; nf < 4; ++nf) {
            int w = pk4fp8(acc[2][r2][nf][0] + biasv, acc[2][r2][nf][1] + biasv,
                           acc[2][r2][nf][2] + biasv, acc[2][r2][nf][3] + biasv);
            size_t tile = (size_t)b * 128 + (n0 >> 5) + (nf >> 1);
            *(unsigned int*)(Vt8 + (tile * 128 + r) * 40 + g * 8 + (nf & 1) * 4) = (unsigned int)w;
        }
    }
}

// ---------------- kernel 2: flash attention (fp8, dbuf, 1 barrier/iter) ----------------
// 16 waves: qw = wv&1 (32 q-rows), grp = wv>>1 (512 keys, 16 tiles of 32).
// smem bytes: Q fp8 [0,8192) 64x128B XOR-swz (DMA, source-swizzled);
//             K fp8 @8192+grp*8192 + p*4096: [32][128B] XOR-swz (DMA, dbuf);
//             V fp8 @73728+grp*10240 + p*5120: [128][40]B image (DMA, dbuf).
// merge overlay (post-loop): l f32 @ byte 0; U bf16 8x[64][132] @ byte 16384.
__global__ __launch_bounds__(1024, 4) void k_attn(
    const unsigned char* __restrict__ Qf, const unsigned char* __restrict__ Kf,
    const unsigned char* __restrict__ Vt8, unsigned short* __restrict__ Ob)
{
    __shared__ __align__(16) unsigned short smem[77824];   // 155648 B
    const int b  = blockIdx.y;
    const int n0 = blockIdx.x * 64;
    const int t  = threadIdx.x;
    const int lane = t & 63, wv_ = t >> 6;        // 16 waves
    const int qw = wv_ & 1, grp = wv_ >> 1;       // 8 KV groups
    const int g = lane >> 4, q16 = lane & 15;

    unsigned char* Ql8 = (unsigned char*)smem;                        // 8KB
    unsigned char* Klb = (unsigned char*)smem + 8192 + grp * 8192;    // 2x4KB
    unsigned char* Vlb = (unsigned char*)smem + 73728 + grp * 10240;  // 2x5KB

    const unsigned char* Qg = Qf + ((size_t)b * N_ + n0) * RC_;
    const unsigned char* Kg = Kf + ((size_t)b * N_ + grp * 512) * RC_;
    const unsigned char* Vg = Vt8 + ((size_t)b * 128 + grp * 16) * 5120;

    // ---- Q stage via DMA: linear dest (byte t*16 within wave), swizzled source ----
    if (t < 512) {
        int row = t >> 3, ch = (t & 7) ^ (row & 7);
        gl_lds16(Qg + row * 128 + ch * 16, (char*)Ql8 + wv_ * 1024);
    }

    // ---- DMA staging into buffer pb_ ----
    #define STAGEK(kt_, pb_) do { int ktc = (kt_);                               \
        unsigned char* kdst = Klb + (pb_) * 4096;                                \
        _Pragma("unroll")                                                        \
        for (int r = 0; r < 2; ++r) {                                            \
            int id = (qw * 2 + r) * 64 + lane;   /* 0..255 chunks of 16B */      \
            int row = id >> 3, ch = id & 7;                                      \
            gl_lds16(Kg + (size_t)(ktc * 32 + row) * RC_ + ((ch ^ (row & 7)) * 16), \
                     kdst + (qw * 2 + r) * 1024);                                \
        }                                                                        \
    } while (0)
    #define STAGEV(kt_, pb_) do { int ktc = (kt_);                               \
        const char* vsrc = (const char*)(Vg + (size_t)ktc * 5120);               \
        char* vdst = (char*)(Vlb + (pb_) * 5120);                                \
        _Pragma("unroll")                                                        \
        for (int j = 0; j < 2; ++j) {                                            \
            int off = j * 2048 + qw * 1024;                                      \
            gl_lds16(vsrc + off + lane * 16, vdst + off);                        \
        }                                                                        \
        if (qw == 0)                                                             \
            gl_lds16(vsrc + 4096 + lane * 16, vdst + 4096);                      \
    } while (0)

    STAGEK(0, 0);
    STAGEV(0, 0);

    f32x4 acc_o[2][8];
    #pragma unroll
    for (int rf = 0; rf < 2; ++rf)
        #pragma unroll
        for (int df = 0; df < 8; ++df)
            acc_o[rf][df] = (f32x4){0.f, 0.f, 0.f, 0.f};
    f32x4 acc_l[2];      // l-rowsums via ones-MFMA: acc_l[rf][i] = l[q=..+g*4+i]
    acc_l[0] = (f32x4){0.f, 0.f, 0.f, 0.f};
    acc_l[1] = (f32x4){0.f, 0.f, 0.f, 0.f};
    const f32x4 z4 = {0.f, 0.f, 0.f, 0.f};               // hoisted zero-C operand
    const long ONES8 = 0x3838383838383838L;              // 8 x fp8 e4m3 1.0

    __syncthreads();   // Q + tile-0 DMA drained

    #pragma unroll 2
    for (int kt = 0; kt < 16; ++kt) {
        const int p = kt & 1;
        if (kt < 15) {
            STAGEK(kt + 1, p ^ 1);
            STAGEV(kt + 1, p ^ 1);
        }
        const unsigned char* Klp = Klb + p * 4096;
        const unsigned char* Vlp = Vlb + p * 5120;

        // S^T = K Q^T (swapped, fp8): lane holds S[q=qblock+q16][k=kf*16+g*4+i].
        // ks=0 uses the zero C operand (no per-iter accumulator zeroing).
        f32x4 s[2][2];
        __builtin_amdgcn_s_setprio(1);
        #pragma unroll
        for (int ks = 0; ks < 4; ++ks) {
            int sw = (((2 * ks + (g >> 1)) ^ (q16 & 7)) * 16) + ((g & 1) * 8);
            long qv0 = *(const long*)&Ql8[(qw * 32 + q16) * 128 + sw];
            long qv1 = *(const long*)&Ql8[(qw * 32 + 16 + q16) * 128 + sw];
            #pragma unroll
            for (int kf = 0; kf < 2; ++kf) {
                long kv = *(const long*)&Klp[(kf * 16 + q16) * 128 + sw];
                s[0][kf] = __builtin_amdgcn_mfma_f32_16x16x32_fp8_fp8(
                    kv, qv0, ks == 0 ? z4 : s[0][kf], 0, 0, 0);
                s[1][kf] = __builtin_amdgcn_mfma_f32_16x16x32_fp8_fp8(
                    kv, qv1, ks == 0 ? z4 : s[1][kf], 0, 0, 0);
            }
        }
        __builtin_amdgcn_s_setprio(0);

        // no-max softmax: p = exp2(S) (SCALEL pre-folded into Q); pack P to fp8
        long pa8[2];
        #pragma unroll
        for (int rf = 0; rf < 2; ++rf) {
            #pragma unroll
            for (int kf = 0; kf < 2; ++kf)
                #pragma unroll
                for (int i = 0; i < 4; ++i)
                    s[rf][kf][i] = exp2f(s[rf][kf][i]);
            int2 pk2;
            pk2.x = pk4fp8(s[rf][0][0], s[rf][0][1], s[rf][0][2], s[rf][0][3]);
            pk2.y = pk4fp8(s[rf][1][0], s[rf][1][1], s[rf][1][2], s[rf][1][3]);
            pa8[rf] = __builtin_bit_cast(long, pk2);
        }

        // O += P @ V (fp8); l += P @ ones (same quantized P as the numerator).
        __builtin_amdgcn_s_setprio(1);
        acc_l[0] = __builtin_amdgcn_mfma_f32_16x16x32_fp8_fp8(pa8[0], ONES8, acc_l[0], 0, 0, 0);
        acc_l[1] = __builtin_amdgcn_mfma_f32_16x16x32_fp8_fp8(pa8[1], ONES8, acc_l[1], 0, 0, 0);
        #pragma unroll
        for (int df = 0; df < 8; ++df) {
            int d = df * 16 + q16;
            long vv = *(const long*)&Vlp[d * 40 + g * 8];
            acc_o[0][df] = __builtin_amdgcn_mfma_f32_16x16x32_fp8_fp8(pa8[0], vv, acc_o[0][df], 0, 0, 0);
            acc_o[1][df] = __builtin_amdgcn_mfma_f32_16x16x32_fp8_fp8(pa8[1], vv, acc_o[1][df], 0, 0, 0);
        }
        __builtin_amdgcn_s_setprio(0);

        __syncthreads();   // drains tile-(kt+1) DMA, fences reuse of buf[p]
    }

    // ---- merge across 8 KV groups ----
    // acc_l[rf][i] = l[q = qw*32 + rf*16 + g*4 + i] (broadcast over q16)
    float* lf = (float*)smem;                       // [8 grp][64 rows]
    unsigned short* Ub = smem + 8192;               // [8 grp][64][132] bf16 @byte 16384
    if (q16 == 0) {
        #pragma unroll
        for (int rf = 0; rf < 2; ++rf)
            #pragma unroll
            for (int i = 0; i < 4; ++i)
                lf[grp * 64 + qw * 32 + rf * 16 + g * 4 + i] = acc_l[rf][i];
    }
    {
        unsigned short* Ug = Ub + grp * 8448;
        #pragma unroll
        for (int rf = 0; rf < 2; ++rf)
            #pragma unroll
            for (int df = 0; df < 8; ++df)
                #pragma unroll
                for (int i = 0; i < 4; ++i)
                    Ug[(qw * 32 + rf * 16 + g * 4 + i) * 132 + df * 16 + q16] =
                        f2bf(acc_o[rf][df][i]);
    }
    __syncthreads();

    // combine: wave wv_ handles q-rows [wv_*4, wv_*4+4), lane covers 2 d-cols
    #pragma unroll
    for (int r = 0; r < 4; ++r) {
        int row = wv_ * 4 + r;
        float lt = 0.f;
        #pragma unroll
        for (int gg = 0; gg < 8; ++gg) lt += lf[gg * 64 + row];
        float inv = 1.f / lt;
        float o0 = 0.f, o1 = 0.f;
        #pragma unroll
        for (int gg = 0; gg < 8; ++gg) {
            unsigned int u = *(const unsigned int*)&Ub[gg * 8448 + row * 132 + lane * 2];
            o0 += __builtin_bit_cast(float, u << 16);
            o1 += __builtin_bit_cast(float, u & 0xffff0000u);
        }
        unsigned int packed = ((unsigned int)f2bf(o1 * inv) << 16) | f2bf(o0 * inv);
        *(unsigned int*)&Ob[((size_t)b * N_ + n0 + row) * RC_ + lane * 2] = packed;
    }
    #undef STAGEK
    #undef STAGEV
}

// ---------------- kernel 3: output projection + residual (NBLK=128; round-19 verified) ----------------
#define QS 136  // 128 + 8 pad (shorts)

__global__ __launch_bounds__(256) void k_out(
    const unsigned short* __restrict__ Ob, const float* __restrict__ wo,
    const float* __restrict__ bo, const float* __restrict__ x,
    const float* __restrict__ gamma, float* __restrict__ out)
{
    __shared__ unsigned short Ol[128 * QS];   // 34.8 KB
    const int b  = blockIdx.z;
    const int c0 = blockIdx.y * 64;
    const int n0 = blockIdx.x * 128;
    const int t  = threadIdx.x;
    const int lane = t & 63, wv_ = t >> 6;
    const int g = lane >> 4, q16 = lane & 15;

    {
        const unsigned short* src = Ob + ((size_t)b * N_ + n0) * RC_;
        #pragma unroll
        for (int p = 0; p < 8; ++p) {
            int row = p * 16 + (t >> 4);
            int s = (t & 15) * 8;
            *(u16x8*)&Ol[row * QS + s] = *(const u16x8*)&src[row * RC_ + s];
        }
    }
    __syncthreads();

    f32x4 acc[8];
    #pragma unroll
    for (int nf = 0; nf < 8; ++nf)
        acc[nf] = (f32x4){0.f, 0.f, 0.f, 0.f};

    const int cw = c0 + wv_ * 16;
    #pragma unroll
    for (int ks = 0; ks < 4; ++ks) {
        u16x8 a8 = ldw8(&wo[(size_t)(cw + q16) * 128 + ks * 32 + g * 8]);
        #pragma unroll
        for (int nf = 0; nf < 8; ++nf) {
            u16x8 b8 = *(const u16x8*)&Ol[(nf * 16 + q16) * QS + ks * 32 + g * 8];
            acc[nf] = mfma16(a8, b8, acc[nf]);
        }
    }

    float gm = gamma[0];
    #pragma unroll
    for (int i = 0; i < 4; ++i) {
        int c = cw + g * 4 + i;
        float bias = bo[c];
        #pragma unroll
        for (int nf = 0; nf < 8; ++nf) {
            int n = n0 + nf * 16 + q16;
            size_t idx = ((size_t)b * C_ + c) * N_ + n;
            out[idx] = gm * (acc[nf][i] + bias) + x[idx];
        }
    }
}

extern "C" void kernel_launch(void* const* d_in, const int* in_sizes, int n_in,
                              void* d_out, int out_size, void* d_ws, size_t ws_size,
                              hipStream_t stream) {
    const float* x     = (const float*)d_in[0];
    const float* wq    = (const float*)d_in[1];
    const float* bq    = (const float*)d_in[2];
    const float* wk    = (const float*)d_in[3];
    const float* bk    = (const float*)d_in[4];
    const float* wv    = (const float*)d_in[5];
    const float* bv    = (const float*)d_in[6];
    const float* wo    = (const float*)d_in[7];
    const float* bo    = (const float*)d_in[8];
    const float* gamma = (const float*)d_in[9];
    float* out = (float*)d_out;

    unsigned char* wsb = (unsigned char*)d_ws;
    unsigned char* Qf  = wsb;                               // [B][N][RC] fp8, 2MB
    unsigned char* Kf  = wsb + 2097152;                     // [B][N][RC] fp8, 2MB
    unsigned char* Vt8 = wsb + 4194304;                     // [B*128][128][40]B fp8 image, 2.62MB
    unsigned short* Ob = (unsigned short*)(wsb + 6815744);  // [B][N][RC] bf16, 4MB

    dim3 g1(64, 4);
    k_qkv<<<g1, 256, 0, stream>>>(x, wq, wk, wv, bq, bk, bv, Qf, Kf, Vt8);
    dim3 g2(64, 4);
    k_attn<<<g2, 1024, 0, stream>>>(Qf, Kf, Vt8, Ob);
    dim3 g3(32, 4, 4);
    k_out<<<g3, 256, 0, stream>>>(Ob, wo, bo, x, gamma, out);
}

// Round 21
// 73.347 us; speedup vs baseline: 1.1452x; 1.1452x over previous
//
#include <hip/hip_runtime.h>
#include <hip/hip_bf16.h>

// SelfAttentionBlock: B=4, C=256, RC=128, H=W=64 (N=4096)
// Round 21: REVERT to the round-19 verified optimum (73.4us). Round 20's
// ones-MFMA l-accumulation + zero-C-operand init regressed k_attn 46.7->57.4us
// (FETCH +8.5MB: accumulator-forwarding broken + register pressure at the
// 128-reg/lane ceiling). This is the best-measured configuration:
//   k_qkv: QBLK=64, fused fp8 Q/K/V production (swapped-operand Q/K, SCALEL
//          folded into Q's quantization, V in PV-image layout);
//   k_attn: 16 waves (2 qw x 8 grp in-block split-KV), fp8 QK^T and PV,
//          no-max exp2 softmax, K/V double-buffered via global_load_lds with
//          ONE barrier/iter, Q DMA-staged (source-swizzled);
//   k_out: NBLK=128, inline f32->bf16 weight conversion, fused residual.

#define B_   4
#define C_   256
#define RC_  128
#define N_   4096
#define SCALEL 0.12750880597462906f                // (1/sqrt(128)) * log2(e)

typedef __bf16 bf16x8 __attribute__((ext_vector_type(8)));
typedef unsigned short u16x8 __attribute__((ext_vector_type(8)));
typedef float f32x4 __attribute__((ext_vector_type(4)));

static __device__ __forceinline__ unsigned short f2bf(float f) {
    unsigned int u = __builtin_bit_cast(unsigned int, f);
    u += 0x7fffu + ((u >> 16) & 1u);
    return (unsigned short)(u >> 16);
}

static __device__ __forceinline__ f32x4 mfma16(u16x8 a, u16x8 b, f32x4 c) {
    return __builtin_amdgcn_mfma_f32_16x16x32_bf16(
        __builtin_bit_cast(bf16x8, a), __builtin_bit_cast(bf16x8, b), c, 0, 0, 0);
}

static __device__ __forceinline__ unsigned int cvtpk(float lo, float hi) {
    unsigned int r;
    asm("v_cvt_pk_bf16_f32 %0, %1, %2" : "=v"(r) : "v"(lo), "v"(hi));
    return r;   // low 16 = bf16(lo), high 16 = bf16(hi), RNE
}

// load 8 consecutive f32 weights and pack to bf16x8 (same RNE as f2bf)
static __device__ __forceinline__ u16x8 ldw8(const float* p) {
    float4 f0 = *(const float4*)p;
    float4 f1 = *(const float4*)(p + 4);
    int4 pk;
    pk.x = (int)cvtpk(f0.x, f0.y);
    pk.y = (int)cvtpk(f0.z, f0.w);
    pk.z = (int)cvtpk(f1.x, f1.y);
    pk.w = (int)cvtpk(f1.z, f1.w);
    return __builtin_bit_cast(u16x8, pk);
}

// pack 4 f32 -> 4 fp8 e4m3 bytes
static __device__ __forceinline__ int pk4fp8(float a, float b, float c, float d) {
    int w = __builtin_amdgcn_cvt_pk_fp8_f32(a, b, 0, false);
    w = __builtin_amdgcn_cvt_pk_fp8_f32(c, d, w, true);
    return w;
}

static __device__ __forceinline__ void gl_lds16(const void* g, void* l) {
    __builtin_amdgcn_global_load_lds(
        (const __attribute__((address_space(1))) void*)g,
        (__attribute__((address_space(3))) void*)l, 16, 0, 0);
}

// ---------------- kernel 1: QKV projection (QBLK=64) ----------------
#define K1_LDA 264  // 256 + 8 pad (shorts)

__global__ __launch_bounds__(256) void k_qkv(
    const float* __restrict__ x,
    const float* __restrict__ wq, const float* __restrict__ wk, const float* __restrict__ wv,
    const float* __restrict__ bq, const float* __restrict__ bk, const float* __restrict__ bv,
    unsigned char* __restrict__ Qf, unsigned char* __restrict__ Kf,
    unsigned char* __restrict__ Vt8)
{
    __shared__ unsigned short lds[64 * K1_LDA];   // 67.6 KB
    const int b  = blockIdx.y;
    const int n0 = blockIdx.x * 64;
    const int t  = threadIdx.x;
    const int lane = t & 63, wv_ = t >> 6;
    const int g = lane >> 4, q16 = lane & 15;

    // stage x[b][c][n0+tok] -> lds[tok][c]; 4 consecutive tokens x 16 channels
    {
        int tk0 = (t & 15) * 4;
        int cb  = (t >> 4) * 16;
        const float* xb = x + ((size_t)b * C_ * N_) + n0 + tk0;
        float4 col[16];
        #pragma unroll
        for (int e = 0; e < 16; ++e)
            col[e] = *(const float4*)&xb[(size_t)(cb + e) * N_];
        #pragma unroll
        for (int tk = 0; tk < 4; ++tk) {
            #pragma unroll
            for (int h = 0; h < 2; ++h) {
                u16x8 v;
                #pragma unroll
                for (int e = 0; e < 8; ++e) {
                    float f = (tk == 0) ? col[h * 8 + e].x : (tk == 1) ? col[h * 8 + e].y
                            : (tk == 2) ? col[h * 8 + e].z : col[h * 8 + e].w;
                    v[e] = f2bf(f);
                }
                *(u16x8*)&lds[(tk0 + tk) * K1_LDA + cb + h * 8] = v;
            }
        }
    }
    __syncthreads();

    f32x4 acc[3][2][4];   // [tq][r2][nf]
    #pragma unroll
    for (int tq = 0; tq < 3; ++tq)
        #pragma unroll
        for (int r2 = 0; r2 < 2; ++r2)
            #pragma unroll
            for (int nf = 0; nf < 4; ++nf)
                acc[tq][r2][nf] = (f32x4){0.f, 0.f, 0.f, 0.f};

    const float* wsrc[3] = {wq, wk, wv};
    const int rbase = wv_ * 32;
    #pragma unroll
    for (int ks = 0; ks < 8; ++ks) {
        u16x8 a[4];
        #pragma unroll
        for (int nf = 0; nf < 4; ++nf)
            a[nf] = *(const u16x8*)&lds[(nf * 16 + q16) * K1_LDA + ks * 32 + g * 8];
        #pragma unroll
        for (int tq = 0; tq < 3; ++tq) {
            const float* w = wsrc[tq];
            #pragma unroll
            for (int r2 = 0; r2 < 2; ++r2) {
                u16x8 bf = ldw8(&w[(size_t)(rbase + r2 * 16 + q16) * 256 + ks * 32 + g * 8]);
                #pragma unroll
                for (int nf = 0; nf < 4; ++nf) {
                    if (tq < 2)
                        acc[tq][r2][nf] = mfma16(bf, a[nf], acc[tq][r2][nf]);  // swapped
                    else
                        acc[tq][r2][nf] = mfma16(a[nf], bf, acc[tq][r2][nf]);
                }
            }
        }
    }

    // Q (pre-scaled by SCALEL), K: fp8 e4m3 dword stores (4 consecutive r/thread)
    #pragma unroll
    for (int r2 = 0; r2 < 2; ++r2) {
        int rb = rbase + r2 * 16 + g * 4;
        float4 bq4 = *(const float4*)&bq[rb];
        float4 bk4 = *(const float4*)&bk[rb];
        #pragma unroll
        for (int nf = 0; nf < 4; ++nf) {
            int n = n0 + nf * 16 + q16;
            int qw32 = pk4fp8((acc[0][r2][nf][0] + bq4.x) * SCALEL,
                              (acc[0][r2][nf][1] + bq4.y) * SCALEL,
                              (acc[0][r2][nf][2] + bq4.z) * SCALEL,
                              (acc[0][r2][nf][3] + bq4.w) * SCALEL);
            int kw32 = pk4fp8(acc[1][r2][nf][0] + bk4.x, acc[1][r2][nf][1] + bk4.y,
                              acc[1][r2][nf][2] + bk4.z, acc[1][r2][nf][3] + bk4.w);
            size_t base = ((size_t)b * N_ + n) * RC_ + rb;
            *(unsigned int*)(Qf + base) = (unsigned int)qw32;
            *(unsigned int*)(Kf + base) = (unsigned int)kw32;
        }
    }

    // V: fp8 e4m3 image, stride 40 B per channel row (round-8-verified mapping).
    #pragma unroll
    for (int r2 = 0; r2 < 2; ++r2) {
        int r = rbase + r2 * 16 + q16;
        float biasv = bv[r];
        #pragma unroll
        for (int nf = 0; nf < 4; ++nf) {
            int w = pk4fp8(acc[2][r2][nf][0] + biasv, acc[2][r2][nf][1] + biasv,
                           acc[2][r2][nf][2] + biasv, acc[2][r2][nf][3] + biasv);
            size_t tile = (size_t)b * 128 + (n0 >> 5) + (nf >> 1);
            *(unsigned int*)(Vt8 + (tile * 128 + r) * 40 + g * 8 + (nf & 1) * 4) = (unsigned int)w;
        }
    }
}

// ---------------- kernel 2: flash attention (fp8, dbuf, 1 barrier/iter) ----------------
// 16 waves: qw = wv&1 (32 q-rows), grp = wv>>1 (512 keys, 16 tiles of 32).
// smem bytes: Q fp8 [0,8192) 64x128B XOR-swz (DMA, source-swizzled);
//             K fp8 @8192+grp*8192 + p*4096: [32][128B] XOR-swz (DMA, dbuf);
//             V fp8 @73728+grp*10240 + p*5120: [128][40]B image (DMA, dbuf).
// merge overlay (post-loop): l f32 @ byte 0; U bf16 8x[64][132] @ byte 16384.
__global__ __launch_bounds__(1024, 4) void k_attn(
    const unsigned char* __restrict__ Qf, const unsigned char* __restrict__ Kf,
    const unsigned char* __restrict__ Vt8, unsigned short* __restrict__ Ob)
{
    __shared__ __align__(16) unsigned short smem[77824];   // 155648 B
    const int b  = blockIdx.y;
    const int n0 = blockIdx.x * 64;
    const int t  = threadIdx.x;
    const int lane = t & 63, wv_ = t >> 6;        // 16 waves
    const int qw = wv_ & 1, grp = wv_ >> 1;       // 8 KV groups
    const int g = lane >> 4, q16 = lane & 15;

    unsigned char* Ql8 = (unsigned char*)smem;                        // 8KB
    unsigned char* Klb = (unsigned char*)smem + 8192 + grp * 8192;    // 2x4KB
    unsigned char* Vlb = (unsigned char*)smem + 73728 + grp * 10240;  // 2x5KB

    const unsigned char* Qg = Qf + ((size_t)b * N_ + n0) * RC_;
    const unsigned char* Kg = Kf + ((size_t)b * N_ + grp * 512) * RC_;
    const unsigned char* Vg = Vt8 + ((size_t)b * 128 + grp * 16) * 5120;

    // ---- Q stage via DMA: linear dest (byte t*16 within wave), swizzled source ----
    if (t < 512) {
        int row = t >> 3, ch = (t & 7) ^ (row & 7);
        gl_lds16(Qg + row * 128 + ch * 16, (char*)Ql8 + wv_ * 1024);
    }

    // ---- DMA staging into buffer pb_ ----
    #define STAGEK(kt_, pb_) do { int ktc = (kt_);                               \
        unsigned char* kdst = Klb + (pb_) * 4096;                                \
        _Pragma("unroll")                                                        \
        for (int r = 0; r < 2; ++r) {                                            \
            int id = (qw * 2 + r) * 64 + lane;   /* 0..255 chunks of 16B */      \
            int row = id >> 3, ch = id & 7;                                      \
            gl_lds16(Kg + (size_t)(ktc * 32 + row) * RC_ + ((ch ^ (row & 7)) * 16), \
                     kdst + (qw * 2 + r) * 1024);                                \
        }                                                                        \
    } while (0)
    #define STAGEV(kt_, pb_) do { int ktc = (kt_);                               \
        const char* vsrc = (const char*)(Vg + (size_t)ktc * 5120);               \
        char* vdst = (char*)(Vlb + (pb_) * 5120);                                \
        _Pragma("unroll")                                                        \
        for (int j = 0; j < 2; ++j) {                                            \
            int off = j * 2048 + qw * 1024;                                      \
            gl_lds16(vsrc + off + lane * 16, vdst + off);                        \
        }                                                                        \
        if (qw == 0)                                                             \
            gl_lds16(vsrc + 4096 + lane * 16, vdst + 4096);                      \
    } while (0)

    STAGEK(0, 0);
    STAGEV(0, 0);

    f32x4 acc_o[2][8];
    #pragma unroll
    for (int rf = 0; rf < 2; ++rf)
        #pragma unroll
        for (int df = 0; df < 8; ++df)
            acc_o[rf][df] = (f32x4){0.f, 0.f, 0.f, 0.f};
    float l_loc[2] = {0.f, 0.f};

    __syncthreads();   // Q + tile-0 DMA drained

    #pragma unroll 2
    for (int kt = 0; kt < 16; ++kt) {
        const int p = kt & 1;
        if (kt < 15) {
            STAGEK(kt + 1, p ^ 1);
            STAGEV(kt + 1, p ^ 1);
        }
        const unsigned char* Klp = Klb + p * 4096;
        const unsigned char* Vlp = Vlb + p * 5120;

        // S^T = K Q^T (swapped, fp8): lane holds S[q=qblock+q16][k=kf*16+g*4+i].
        f32x4 s[2][2];
        #pragma unroll
        for (int rf = 0; rf < 2; ++rf)
            #pragma unroll
            for (int kf = 0; kf < 2; ++kf)
                s[rf][kf] = (f32x4){0.f, 0.f, 0.f, 0.f};
        __builtin_amdgcn_s_setprio(1);
        #pragma unroll
        for (int ks = 0; ks < 4; ++ks) {
            int sw = (((2 * ks + (g >> 1)) ^ (q16 & 7)) * 16) + ((g & 1) * 8);
            long qv0 = *(const long*)&Ql8[(qw * 32 + q16) * 128 + sw];
            long qv1 = *(const long*)&Ql8[(qw * 32 + 16 + q16) * 128 + sw];
            #pragma unroll
            for (int kf = 0; kf < 2; ++kf) {
                long kv = *(const long*)&Klp[(kf * 16 + q16) * 128 + sw];
                s[0][kf] = __builtin_amdgcn_mfma_f32_16x16x32_fp8_fp8(kv, qv0, s[0][kf], 0, 0, 0);
                s[1][kf] = __builtin_amdgcn_mfma_f32_16x16x32_fp8_fp8(kv, qv1, s[1][kf], 0, 0, 0);
            }
        }
        __builtin_amdgcn_s_setprio(0);

        // no-max softmax: p = exp2(S) (SCALEL pre-folded into Q); pack P to fp8
        long pa8[2];
        #pragma unroll
        for (int rf = 0; rf < 2; ++rf) {
            #pragma unroll
            for (int kf = 0; kf < 2; ++kf)
                #pragma unroll
                for (int i = 0; i < 4; ++i)
                    s[rf][kf][i] = exp2f(s[rf][kf][i]);
            l_loc[rf] += (s[rf][0][0] + s[rf][0][1]) + (s[rf][0][2] + s[rf][0][3])
                       + (s[rf][1][0] + s[rf][1][1]) + (s[rf][1][2] + s[rf][1][3]);
            int2 pk2;
            pk2.x = pk4fp8(s[rf][0][0], s[rf][0][1], s[rf][0][2], s[rf][0][3]);
            pk2.y = pk4fp8(s[rf][1][0], s[rf][1][1], s[rf][1][2], s[rf][1][3]);
            pa8[rf] = __builtin_bit_cast(long, pk2);
        }

        // O += P @ V (fp8). V image row d: lane's 8 byte-slots at g*8 (one b64).
        __builtin_amdgcn_s_setprio(1);
        #pragma unroll
        for (int df = 0; df < 8; ++df) {
            int d = df * 16 + q16;
            long vv = *(const long*)&Vlp[d * 40 + g * 8];
            acc_o[0][df] = __builtin_amdgcn_mfma_f32_16x16x32_fp8_fp8(pa8[0], vv, acc_o[0][df], 0, 0, 0);
            acc_o[1][df] = __builtin_amdgcn_mfma_f32_16x16x32_fp8_fp8(pa8[1], vv, acc_o[1][df], 0, 0, 0);
        }
        __builtin_amdgcn_s_setprio(0);

        __syncthreads();   // drains tile-(kt+1) DMA, fences reuse of buf[p]
    }

    // ---- merge across 8 KV groups ----
    float l0 = l_loc[0], l1 = l_loc[1];
    l0 += __shfl_xor(l0, 16); l0 += __shfl_xor(l0, 32);
    l1 += __shfl_xor(l1, 16); l1 += __shfl_xor(l1, 32);

    float* lf = (float*)smem;                       // [8 grp][64 rows]
    unsigned short* Ub = smem + 8192;               // [8 grp][64][132] bf16 @byte 16384
    if (g == 0) {
        lf[grp * 64 + qw * 32 + q16]      = l0;
        lf[grp * 64 + qw * 32 + 16 + q16] = l1;
    }
    {
        unsigned short* Ug = Ub + grp * 8448;
        #pragma unroll
        for (int rf = 0; rf < 2; ++rf)
            #pragma unroll
            for (int df = 0; df < 8; ++df)
                #pragma unroll
                for (int i = 0; i < 4; ++i)
                    Ug[(qw * 32 + rf * 16 + g * 4 + i) * 132 + df * 16 + q16] =
                        f2bf(acc_o[rf][df][i]);
    }
    __syncthreads();

    // combine: wave wv_ handles q-rows [wv_*4, wv_*4+4), lane covers 2 d-cols
    #pragma unroll
    for (int r = 0; r < 4; ++r) {
        int row = wv_ * 4 + r;
        float lt = 0.f;
        #pragma unroll
        for (int gg = 0; gg < 8; ++gg) lt += lf[gg * 64 + row];
        float inv = 1.f / lt;
        float o0 = 0.f, o1 = 0.f;
        #pragma unroll
        for (int gg = 0; gg < 8; ++gg) {
            unsigned int u = *(const unsigned int*)&Ub[gg * 8448 + row * 132 + lane * 2];
            o0 += __builtin_bit_cast(float, u << 16);
            o1 += __builtin_bit_cast(float, u & 0xffff0000u);
        }
        unsigned int packed = ((unsigned int)f2bf(o1 * inv) << 16) | f2bf(o0 * inv);
        *(unsigned int*)&Ob[((size_t)b * N_ + n0 + row) * RC_ + lane * 2] = packed;
    }
    #undef STAGEK
    #undef STAGEV
}

// ---------------- kernel 3: output projection + residual (NBLK=128) ----------------
#define QS 136  // 128 + 8 pad (shorts)

__global__ __launch_bounds__(256) void k_out(
    const unsigned short* __restrict__ Ob, const float* __restrict__ wo,
    const float* __restrict__ bo, const float* __restrict__ x,
    const float* __restrict__ gamma, float* __restrict__ out)
{
    __shared__ unsigned short Ol[128 * QS];   // 34.8 KB
    const int b  = blockIdx.z;
    const int c0 = blockIdx.y * 64;
    const int n0 = blockIdx.x * 128;
    const int t  = threadIdx.x;
    const int lane = t & 63, wv_ = t >> 6;
    const int g = lane >> 4, q16 = lane & 15;

    {
        const unsigned short* src = Ob + ((size_t)b * N_ + n0) * RC_;
        #pragma unroll
        for (int p = 0; p < 8; ++p) {
            int row = p * 16 + (t >> 4);
            int s = (t & 15) * 8;
            *(u16x8*)&Ol[row * QS + s] = *(const u16x8*)&src[row * RC_ + s];
        }
    }
    __syncthreads();

    f32x4 acc[8];
    #pragma unroll
    for (int nf = 0; nf < 8; ++nf)
        acc[nf] = (f32x4){0.f, 0.f, 0.f, 0.f};

    const int cw = c0 + wv_ * 16;
    #pragma unroll
    for (int ks = 0; ks < 4; ++ks) {
        u16x8 a8 = ldw8(&wo[(size_t)(cw + q16) * 128 + ks * 32 + g * 8]);
        #pragma unroll
        for (int nf = 0; nf < 8; ++nf) {
            u16x8 b8 = *(const u16x8*)&Ol[(nf * 16 + q16) * QS + ks * 32 + g * 8];
            acc[nf] = mfma16(a8, b8, acc[nf]);
        }
    }

    float gm = gamma[0];
    #pragma unroll
    for (int i = 0; i < 4; ++i) {
        int c = cw + g * 4 + i;
        float bias = bo[c];
        #pragma unroll
        for (int nf = 0; nf < 8; ++nf) {
            int n = n0 + nf * 16 + q16;
            size_t idx = ((size_t)b * C_ + c) * N_ + n;
            out[idx] = gm * (acc[nf][i] + bias) + x[idx];
        }
    }
}

extern "C" void kernel_launch(void* const* d_in, const int* in_sizes, int n_in,
                              void* d_out, int out_size, void* d_ws, size_t ws_size,
                              hipStream_t stream) {
    const float* x     = (const float*)d_in[0];
    const float* wq    = (const float*)d_in[1];
    const float* bq    = (const float*)d_in[2];
    const float* wk    = (const float*)d_in[3];
    const float* bk    = (const float*)d_in[4];
    const float* wv    = (const float*)d_in[5];
    const float* bv    = (const float*)d_in[6];
    const float* wo    = (const float*)d_in[7];
    const float* bo    = (const float*)d_in[8];
    const float* gamma = (const float*)d_in[9];
    float* out = (float*)d_out;

    unsigned char* wsb = (unsigned char*)d_ws;
    unsigned char* Qf  = wsb;                               // [B][N][RC] fp8, 2MB
    unsigned char* Kf  = wsb + 2097152;                     // [B][N][RC] fp8, 2MB
    unsigned char* Vt8 = wsb + 4194304;                     // [B*128][128][40]B fp8 image, 2.62MB
    unsigned short* Ob = (unsigned short*)(wsb + 6815744);  // [B][N][RC] bf16, 4MB

    dim3 g1(64, 4);
    k_qkv<<<g1, 256, 0, stream>>>(x, wq, wk, wv, bq, bk, bv, Qf, Kf, Vt8);
    dim3 g2(64, 4);
    k_attn<<<g2, 1024, 0, stream>>>(Qf, Kf, Vt8, Ob);
    dim3 g3(32, 4, 4);
    k_out<<<g3, 256, 0, stream>>>(Ob, wo, bo, x, gamma, out);
}